// Round 8
// baseline (1434.875 us; speedup 1.0000x reference)
//
#include <hip/hip_runtime.h>
#include <math.h>

#define MDIM   4096
#define NSTEPS 199
#define NBLK   256     // one block per CU
#define NTHR   1024    // 16 waves
#define B1C    0.9f
#define B2C    0.999f
#define EPSC   1e-8f

typedef unsigned long long u64;

// ---------------------------------------------------------------------------
// Init: u0 = 1 - mean; flags row 0 preset to 1 (u_0 ready by stream order),
// rows 1..NSTEPS zeroed. Visibility to the persistent kernel is by stream
// order + kernel-boundary cache writeback (idiom validated rounds 0/3/6).
// ---------------------------------------------------------------------------
__global__ void init_state(const float* __restrict__ mean,
                           float* __restrict__ u0,
                           int* __restrict__ flags, int nflags) {
    int i = blockIdx.x * blockDim.x + threadIdx.x;
    if (i < MDIM)   u0[i] = 1.0f - mean[i];
    if (i < nflags) flags[i] = (i < NBLK) ? 1 : 0;
}

// ---------------------------------------------------------------------------
// Persistent cooperative kernel — sparse per-lane flag wait + B_go barrier.
//
// ROUND-7 LESSON: the sparse wait itself is fine (poll rate ~0.6 req/ns/line,
// at the proven go-line rate), but the u load MUST be separated from the
// relaxed flag load by __syncthreads — every passing kernel (r0/r3/r6) had
// a barrier there; r7 removed it and failed (relaxed atomics to different
// addresses are unordered for the compiler; the u load could be scheduled
// into the spin window). B_go restores the exact validated ordering shape
// AND makes this r3's full barrier with the aggregator deleted:
//
//   producer: u store -> B2 (per-wave vmcnt(0) drain) -> flag[t][bid] store
//   consumer: lane polls flag[t-1][pb] (its sole producer) -> B_go
//             (all 1024 lanes collectively = all 256 flags seen) -> u load
//
// Correctness = r3's proof verbatim: after B_go every block completed t-1,
// hence finished reading u_{t-2} -> overwriting that buffer is WAR-safe;
// flag follows the drained stores -> RAW-safe. No transitivity needed.
//
// Chain after last producer: flag store (1 leg) -> lane detect (~1.5) ->
// B_go (~0.1) -> u load (1)  vs  r3's 5+ legs (agg detect + go store + go
// detect removed). Poll traffic: wave w's 64 lanes load 16 consecutive
// words (64 B); 2 req/line/block/round over 8 lines, s_sleep-paced.
//
// Compute: r3's validated segment dot — wave w of block b holds
// Q[16b..16b+15][256w+4l..+3] in 64 regs/lane, built by the r4-validated
// fused prologue (0.5*(va[r][c]+va[c][r]), bit-identical to prep_qs);
// u is 16 B/lane; 30-shuffle fold + 16x17 pr matrix; Adam in registers.
// ---------------------------------------------------------------------------
__global__ __launch_bounds__(NTHR) void adam_persist(
        const float* __restrict__ va,
        float* u0, float* u1,
        const float* __restrict__ mean,
        float* __restrict__ w_out,
        int* __restrict__ flags) {
    __shared__ float pr[2][16][17];   // [buf][wave][local row], +1 pad

    const int tid  = threadIdx.x;
    const int bid  = blockIdx.x;
    const int wave = tid >> 6;
    const int lane = tid & 63;
    const int row  = bid * 16 + wave;
    const int col0 = wave * 256 + lane * 4;    // this lane's 4-element segment
    const int pb   = col0 >> 4;                // sole producer of those 4 cols

    // ---- one-time fused Q prologue (validated round 4) ----
    // qreg[r] = 0.5*(va[16b+r][col0..+3] + va[col0..+3][16b+r])
    float4 qreg[16];
#pragma unroll
    for (int r = 0; r < 16; ++r)
        qreg[r] = *(const float4*)(va + (size_t)(bid * 16 + r) * MDIM + col0);

#define XPOSE(c, comp)                                                        \
    {                                                                         \
        const float* vp = va + (size_t)(col0 + (c)) * MDIM + bid * 16;        \
        float4 a0 = *(const float4*)(vp + 0);                                 \
        float4 a1 = *(const float4*)(vp + 4);                                 \
        float4 a2 = *(const float4*)(vp + 8);                                 \
        float4 a3 = *(const float4*)(vp + 12);                                \
        float tv[16] = {a0.x, a0.y, a0.z, a0.w, a1.x, a1.y, a1.z, a1.w,       \
                        a2.x, a2.y, a2.z, a2.w, a3.x, a3.y, a3.z, a3.w};      \
        _Pragma("unroll")                                                     \
        for (int r = 0; r < 16; ++r)                                          \
            qreg[r].comp = 0.5f * (qreg[r].comp + tv[r]);                     \
    }
    XPOSE(0, x) XPOSE(1, y) XPOSE(2, z) XPOSE(3, w)
#undef XPOSE

    float m = 0.0f, v = 0.0f, b1p = 1.0f, b2p = 1.0f;
    const float mrow = mean[row];
    float ucur = 1.0f - mrow;                  // u[row] lives in registers

    for (int t = 1; t <= NSTEPS; ++t) {
        const float* uin = (t & 1) ? u0 : u1;  // t=1 reads u0
        float*      uout = (t & 1) ? u1 : u0;  // u_t lands in buffer t&1
        const int b = t & 1;

        // ---- sparse wait: ONE flag word per lane, wave-coalesced ----
        {
            const int* f = flags + (size_t)(t - 1) * NBLK + pb;
            int spin = 0;
            while (__hip_atomic_load(f, __ATOMIC_RELAXED,
                                     __HIP_MEMORY_SCOPE_AGENT) == 0) {
                if (++spin > 8) __builtin_amdgcn_s_sleep(1);  // pace poll traffic
                if (spin > (1 << 22)) break;   // fail visibly, never hang
            }
        }
        // B_go: the validated separator between flag observation and data
        // load (compiler motion barrier + all-lanes rendezvous = all 256
        // producers done). DO NOT REMOVE — round 7 failed without it.
        __syncthreads();

        // ---- u load: exactly one 16B read per lane per step ----
        u64 d0 = __hip_atomic_load((const u64*)(uin + col0),     __ATOMIC_RELAXED, __HIP_MEMORY_SCOPE_AGENT);
        u64 d1 = __hip_atomic_load((const u64*)(uin + col0 + 2), __ATOMIC_RELAXED, __HIP_MEMORY_SCOPE_AGENT);
        const float uv0 = __uint_as_float((unsigned)d0);
        const float uv1 = __uint_as_float((unsigned)(d0 >> 32));
        const float uv2 = __uint_as_float((unsigned)d1);
        const float uv3 = __uint_as_float((unsigned)(d1 >> 32));

        // ---- 16 row-partials over this lane's 4 columns ----
        float acc[16];
#pragma unroll
        for (int r = 0; r < 16; ++r) {
            float4 q = qreg[r];
            acc[r] = q.x * uv0 + q.y * uv1 + q.z * uv2 + q.w * uv3;
        }

        // ---- fold 16 values x 64 lanes -> 1 value/lane (30 shuffles) ----
#pragma unroll
        for (int stage = 0; stage < 4; ++stage) {
            const int mask = 32 >> stage;
            const int half = 8 >> stage;
            const bool hi = (lane & mask) != 0;
#pragma unroll
            for (int i = 0; i < half; ++i) {
                float plo = __shfl_xor(acc[i],        mask);
                float phi = __shfl_xor(acc[i + half], mask);
                acc[i] = hi ? (acc[i + half] + phi) : (acc[i] + plo);
            }
        }
        float acc0 = acc[0];
        acc0 += __shfl_xor(acc0, 1);   // finish sum within the quad
        acc0 += __shfl_xor(acc0, 2);

        if ((lane & 3) == 0) pr[b][wave][lane >> 2] = acc0;
        __syncthreads();               // B1: pr matrix ready

        // ---- cross-wave fold: wave w reduces local row w; Adam in regs ----
        float unew = ucur;
        if (lane < 16) {
            float p = pr[b][lane][wave];
            p += __shfl_xor(p, 1);
            p += __shfl_xor(p, 2);
            p += __shfl_xor(p, 4);
            p += __shfl_xor(p, 8);
            const float g = p;

            b1p *= B1C;
            b2p *= B2C;
            m = B1C * m + (1.0f - B1C) * g;
            v = B2C * v + (1.0f - B2C) * g * g;
            const float denom = sqrtf(v) / sqrtf(1.0f - b2p) + EPSC;
            unew = ucur - (0.1f / (1.0f - b1p)) * m / denom;
            ucur = unew;
        }

        if (t < NSTEPS) {              // nobody consumes u_199 from memory
            if (lane == 0)
                __hip_atomic_store(uout + row, unew, __ATOMIC_RELAXED,
                                   __HIP_MEMORY_SCOPE_AGENT);
            // B2: each wave's s_waitcnt vmcnt(0) before s_barrier drains its
            // u store -> flag below implies all 16 rows agent-visible.
            __syncthreads();

            if (tid == 0)
                __hip_atomic_store(flags + (size_t)t * NBLK + bid, 1,
                                   __ATOMIC_RELAXED, __HIP_MEMORY_SCOPE_AGENT);
        }
    }

    if (lane == 0) w_out[row] = ucur + mrow;
}

extern "C" void kernel_launch(void* const* d_in, const int* in_sizes, int n_in,
                              void* d_out, int out_size, void* d_ws, size_t ws_size,
                              hipStream_t stream) {
    const float* mean = (const float*)d_in[0];   // (4096,)
    const float* va   = (const float*)d_in[1];   // (4096,4096)
    float* w_out = (float*)d_out;                // (4096,)

    float* ws = (float*)d_ws;
    float* u0  = ws;                              // 16 KB
    float* u1  = u0 + MDIM;                       // 16 KB
    int*   flg = (int*)(u1 + MDIM);               // (NSTEPS+1)*256 ints

    const int nflags = (NSTEPS + 1) * NBLK;

    init_state<<<(nflags + 255) / 256, 256, 0, stream>>>(mean, u0, flg, nflags);

    void* args[] = { (void*)&va, (void*)&u0, (void*)&u1,
                     (void*)&mean, (void*)&w_out, (void*)&flg };
    hipLaunchCooperativeKernel((const void*)adam_persist,
                               dim3(NBLK), dim3(NTHR), args, 0, stream);
}

// Round 9
// 1385.419 us; speedup vs baseline: 1.0357x; 1.0357x over previous
//
#include <hip/hip_runtime.h>
#include <math.h>

#define MDIM   4096
#define NSTEPS 199
#define NBLK   256     // one block per CU
#define NTHR   1024    // 16 waves
#define B1C    0.9f
#define B2C    0.999f
#define EPSC   1e-8f
#define CPAD   32      // pad counters/go to one 128B line each

typedef unsigned long long u64;

// ---------------------------------------------------------------------------
// Prep: Qs[i][j] = 0.5*(va[i][j] + va[j][i]), LDS-tiled transpose (validated).
// ---------------------------------------------------------------------------
__global__ void prep_qs(const float* __restrict__ va, float* __restrict__ Qs) {
    __shared__ float tile[32][33];
    const int j0 = blockIdx.x * 32;
    const int i0 = blockIdx.y * 32;
    const int tx = threadIdx.x, ty = threadIdx.y;

    for (int k = 0; k < 32; k += 8)
        tile[ty + k][tx] = va[(size_t)(j0 + ty + k) * MDIM + i0 + tx];
    __syncthreads();
    for (int k = 0; k < 32; k += 8) {
        int i = i0 + ty + k;
        float a = va[(size_t)i * MDIM + j0 + tx];
        float b = tile[tx][ty + k];          // va[j][i]
        Qs[(size_t)i * MDIM + j0 + tx] = 0.5f * (a + b);
    }
}

// ---------------------------------------------------------------------------
// Init: u0 = 1 - mean; cnt/go arrays zeroed, go[0] preset (u_0 ready by
// stream order + kernel-boundary writeback — idiom validated r0/r3/r6).
// Layout: cnt[t] at sync[t*CPAD] (RMW-only line, NEVER polled);
//         go[t]  at sync[(NSTEPS+1+t)*CPAD] (1 writer, 1 poller/block).
// ---------------------------------------------------------------------------
__global__ void init_state(const float* __restrict__ mean,
                           float* __restrict__ u0,
                           int* __restrict__ sync, int nsync) {
    int i = blockIdx.x * blockDim.x + threadIdx.x;
    if (i < MDIM)  u0[i] = 1.0f - mean[i];
    if (i < nsync) sync[i] = (i == (NSTEPS + 1) * CPAD) ? 1 : 0; // go[0]=1
}

// ---------------------------------------------------------------------------
// Persistent cooperative kernel — r3 champion with ONE change: the
// aggregator block is replaced by last-producer-sets-go.
//
//   producer: u store -> B2 (per-wave vmcnt(0) drain; validated release
//             idiom) -> tid0: old = fetch_add(cnt[t], 1, relaxed agent);
//             if (old == NBLK-1) store go[t] = 1.
//   consumer: tid0 polls go[t-1] (ONE line, ONE poller/block — r3's proven
//             pattern) -> B_go -> u load.
//
// Deconfounding r5: cnt[t] lives on its OWN 128B line with ZERO pollers
// (r5 put 256 pollers + 256 RMWs on one line); go[t] on its own line.
// Ordering: go store is issued only after the last RMW's returned value
// (s_waitcnt data dependence), and every add follows its block's B2 drain
// -> go visible implies all 256 drains complete implies u_t visible.
// Removes r3's aggregator-detect + its extra hop (~1-1.4 us/step).
// Compute: r3's validated segment dot (Q in 64 regs/lane, u 16 B/lane,
// 30-shuffle fold + 16x17 pr matrix, Adam in registers).
// ---------------------------------------------------------------------------
__global__ __launch_bounds__(NTHR) void adam_persist(
        const float* __restrict__ Qs,
        float* u0, float* u1,
        const float* __restrict__ mean,
        float* __restrict__ w_out,
        int* __restrict__ sync) {
    __shared__ float pr[2][16][17];   // [buf][wave][local row], +1 pad

    const int tid  = threadIdx.x;
    const int bid  = blockIdx.x;
    const int wave = tid >> 6;
    const int lane = tid & 63;
    const int row  = bid * 16 + wave;
    const int col0 = wave * 256 + lane * 4;    // this lane's 4-element segment

    int* cnt = sync;                            // cnt[t] at cnt[t*CPAD]
    int* go  = sync + (NSTEPS + 1) * CPAD;      // go[t]  at go[t*CPAD]

    // ---- one-time: Q fragment -> registers (64 regs/lane) ----
    float4 qreg[16];
#pragma unroll
    for (int r = 0; r < 16; ++r)
        qreg[r] = *(const float4*)(Qs + (size_t)(bid * 16 + r) * MDIM + col0);

    float m = 0.0f, v = 0.0f, b1p = 1.0f, b2p = 1.0f;
    const float mrow = mean[row];
    float ucur = 1.0f - mrow;                  // u[row] lives in registers

    for (int t = 1; t <= NSTEPS; ++t) {
        const float* uin = (t & 1) ? u0 : u1;  // t=1 reads u0
        float*      uout = (t & 1) ? u1 : u0;  // u_t lands in buffer t&1
        const int b = t & 1;

        // ---- wait: ONE poller per block on ONE line (proven pattern) ----
        if (tid == 0) {
            int spin = 0;
            while (__hip_atomic_load(go + (size_t)(t - 1) * CPAD,
                                     __ATOMIC_RELAXED,
                                     __HIP_MEMORY_SCOPE_AGENT) == 0) {
                if (++spin > (1 << 24)) break;   // fail visibly, never hang
            }
        }
        __syncthreads();               // B_go: u_{t-1} visible to all lanes
                                       // (validated separator — r7 lesson)

        // ---- load u segment (2x8B agent atomics bypass stale L2) ----
        u64 d0 = __hip_atomic_load((const u64*)(uin + col0),     __ATOMIC_RELAXED, __HIP_MEMORY_SCOPE_AGENT);
        u64 d1 = __hip_atomic_load((const u64*)(uin + col0 + 2), __ATOMIC_RELAXED, __HIP_MEMORY_SCOPE_AGENT);
        const float uv0 = __uint_as_float((unsigned)d0);
        const float uv1 = __uint_as_float((unsigned)(d0 >> 32));
        const float uv2 = __uint_as_float((unsigned)d1);
        const float uv3 = __uint_as_float((unsigned)(d1 >> 32));

        // ---- 16 row-partials over this lane's 4 columns ----
        float acc[16];
#pragma unroll
        for (int r = 0; r < 16; ++r) {
            float4 q = qreg[r];
            acc[r] = q.x * uv0 + q.y * uv1 + q.z * uv2 + q.w * uv3;
        }

        // ---- fold 16 values x 64 lanes -> 1 value/lane (30 shuffles) ----
#pragma unroll
        for (int stage = 0; stage < 4; ++stage) {
            const int mask = 32 >> stage;
            const int half = 8 >> stage;
            const bool hi = (lane & mask) != 0;
#pragma unroll
            for (int i = 0; i < half; ++i) {
                float plo = __shfl_xor(acc[i],        mask);
                float phi = __shfl_xor(acc[i + half], mask);
                acc[i] = hi ? (acc[i + half] + phi) : (acc[i] + plo);
            }
        }
        float acc0 = acc[0];
        acc0 += __shfl_xor(acc0, 1);   // finish sum within the quad
        acc0 += __shfl_xor(acc0, 2);

        if ((lane & 3) == 0) pr[b][wave][lane >> 2] = acc0;
        __syncthreads();               // B1: pr matrix ready

        // ---- cross-wave fold: wave w reduces local row w; Adam in regs ----
        float unew = ucur;
        if (lane < 16) {
            float p = pr[b][lane][wave];
            p += __shfl_xor(p, 1);
            p += __shfl_xor(p, 2);
            p += __shfl_xor(p, 4);
            p += __shfl_xor(p, 8);
            const float g = p;

            b1p *= B1C;
            b2p *= B2C;
            m = B1C * m + (1.0f - B1C) * g;
            v = B2C * v + (1.0f - B2C) * g * g;
            const float denom = sqrtf(v) / sqrtf(1.0f - b2p) + EPSC;
            unew = ucur - (0.1f / (1.0f - b1p)) * m / denom;
            ucur = unew;
        }

        if (t < NSTEPS) {              // nobody consumes u_199 from memory
            if (lane == 0)
                __hip_atomic_store(uout + row, unew, __ATOMIC_RELAXED,
                                   __HIP_MEMORY_SCOPE_AGENT);
            // B2: each wave's s_waitcnt vmcnt(0) before s_barrier drains its
            // u store -> the add below implies all 16 rows agent-visible.
            __syncthreads();

            if (tid == 0) {
                int old = __hip_atomic_fetch_add(cnt + (size_t)t * CPAD, 1,
                                                 __ATOMIC_RELAXED,
                                                 __HIP_MEMORY_SCOPE_AGENT);
                if (old == NBLK - 1)   // last producer releases everyone
                    __hip_atomic_store(go + (size_t)t * CPAD, 1,
                                       __ATOMIC_RELAXED,
                                       __HIP_MEMORY_SCOPE_AGENT);
            }
        }
    }

    if (lane == 0) w_out[row] = ucur + mrow;
}

extern "C" void kernel_launch(void* const* d_in, const int* in_sizes, int n_in,
                              void* d_out, int out_size, void* d_ws, size_t ws_size,
                              hipStream_t stream) {
    const float* mean = (const float*)d_in[0];   // (4096,)
    const float* va   = (const float*)d_in[1];   // (4096,4096)
    float* w_out = (float*)d_out;                // (4096,)

    float* ws = (float*)d_ws;
    float* Qs  = ws;                              // 64 MB
    float* u0  = ws + (size_t)MDIM * MDIM;        // 16 KB
    float* u1  = u0 + MDIM;                       // 16 KB
    int*   syn = (int*)(u1 + MDIM);               // 2*(NSTEPS+1)*CPAD ints

    const int nsync = 2 * (NSTEPS + 1) * CPAD;

    prep_qs<<<dim3(MDIM / 32, MDIM / 32), dim3(32, 8), 0, stream>>>(va, Qs);
    init_state<<<(nsync + 255) / 256, 256, 0, stream>>>(mean, u0, syn, nsync);

    void* args[] = { (void*)&Qs, (void*)&u0, (void*)&u1,
                     (void*)&mean, (void*)&w_out, (void*)&syn };
    hipLaunchCooperativeKernel((const void*)adam_persist,
                               dim3(NBLK), dim3(NTHR), args, 0, stream);
}

// Round 10
// 976.309 us; speedup vs baseline: 1.4697x; 1.4190x over previous
//
#include <hip/hip_runtime.h>
#include <math.h>

#define MDIM   4096
#define NSTEPS 199
#define NBLK   256     // one block per CU
#define NTHR   1024    // 16 waves
#define B1C    0.9f
#define B2C    0.999f
#define EPSC   1e-8f

typedef unsigned long long u64;

// ---------------------------------------------------------------------------
// Init: u0 = 1 - mean; zero flags and go (per-step slots, no reset races).
// ---------------------------------------------------------------------------
__global__ void init_state(const float* __restrict__ mean,
                           float* __restrict__ u0,
                           int* __restrict__ flags, int nflags) {
    int i = blockIdx.x * blockDim.x + threadIdx.x;
    if (i < MDIM)   u0[i] = 1.0f - mean[i];
    if (i < nflags) flags[i] = 0;
}

// ---------------------------------------------------------------------------
// Persistent cooperative kernel — r3 champion sync (the measured optimum of
// 7 tested structures) + fused Q prologue (r8-validated numerics).
//
// SYNC LEDGER (step µs): r3 flag+aggregator+go = 4.3 | flat polls 5.3-5.75 |
// counter RMW 6.4 (RMW serialization ~8ns/arrival, polled or not) |
// sparse per-lane 6.6 | data-polling 7.7-14.5 (line-rate storms).
// Rules: readiness = contention-free STORES; ≤1 poller/block/line at
// ≲256 req/line/round; barrier between flag observation and data load.
// DO NOT MODIFY THE SYNC — every deviation measured worse.
//
// Per step: compute dot from registers (Q fragment 64 regs/lane, u segment
// 16 B/lane), 30-shuffle fold + 16x17 pr matrix, Adam in registers,
// publish u[row], B2 (vmcnt-drain release), flag store; block 0's wave 0
// aggregates 256 flags -> go[t]; consumers poll go with one lane; B3;
// load next u segment.
// ---------------------------------------------------------------------------
__global__ __launch_bounds__(NTHR) void adam_persist(
        const float* __restrict__ va,
        float* u0, float* u1,
        const float* __restrict__ mean,
        float* __restrict__ w_out,
        int* __restrict__ flags, int* __restrict__ go) {
    __shared__ float pr[2][16][17];   // [buf][wave][local row], +1 pad

    const int tid  = threadIdx.x;
    const int bid  = blockIdx.x;
    const int wave = tid >> 6;
    const int lane = tid & 63;
    const int row  = bid * 16 + wave;
    const int col0 = wave * 256 + lane * 4;    // this lane's 4-element segment

    // ---- one-time fused Q prologue (validated in passing r8 kernel) ----
    // qreg[r] = 0.5*(va[16b+r][col0..+3] + va[col0..+3][16b+r])
    float4 qreg[16];
#pragma unroll
    for (int r = 0; r < 16; ++r)
        qreg[r] = *(const float4*)(va + (size_t)(bid * 16 + r) * MDIM + col0);

#define XPOSE(c, comp)                                                        \
    {                                                                         \
        const float* vp = va + (size_t)(col0 + (c)) * MDIM + bid * 16;        \
        float4 a0 = *(const float4*)(vp + 0);                                 \
        float4 a1 = *(const float4*)(vp + 4);                                 \
        float4 a2 = *(const float4*)(vp + 8);                                 \
        float4 a3 = *(const float4*)(vp + 12);                                \
        float tv[16] = {a0.x, a0.y, a0.z, a0.w, a1.x, a1.y, a1.z, a1.w,       \
                        a2.x, a2.y, a2.z, a2.w, a3.x, a3.y, a3.z, a3.w};      \
        _Pragma("unroll")                                                     \
        for (int r = 0; r < 16; ++r)                                          \
            qreg[r].comp = 0.5f * (qreg[r].comp + tv[r]);                     \
    }
    XPOSE(0, x) XPOSE(1, y) XPOSE(2, z) XPOSE(3, w)
#undef XPOSE

    float m = 0.0f, v = 0.0f, b1p = 1.0f, b2p = 1.0f;
    const float mrow = mean[row];
    float ucur = 1.0f - mrow;                  // u[row] lives in registers

    // ---- u_0 segment -> registers (agent atomics bypass stale caches) ----
    float uv0, uv1, uv2, uv3;
    {
        u64 d0 = __hip_atomic_load((const u64*)(u0 + col0),     __ATOMIC_RELAXED, __HIP_MEMORY_SCOPE_AGENT);
        u64 d1 = __hip_atomic_load((const u64*)(u0 + col0 + 2), __ATOMIC_RELAXED, __HIP_MEMORY_SCOPE_AGENT);
        uv0 = __uint_as_float((unsigned)d0);  uv1 = __uint_as_float((unsigned)(d0 >> 32));
        uv2 = __uint_as_float((unsigned)d1);  uv3 = __uint_as_float((unsigned)(d1 >> 32));
    }

    for (int t = 1; t <= NSTEPS; ++t) {
        float* uout = (t & 1) ? u1 : u0;       // u_t lands in buffer t&1
        const int b = t & 1;

        // ---- 16 row-partials over this lane's 4 columns ----
        float acc[16];
#pragma unroll
        for (int r = 0; r < 16; ++r) {
            float4 q = qreg[r];
            acc[r] = q.x * uv0 + q.y * uv1 + q.z * uv2 + q.w * uv3;
        }

        // ---- fold 16 values x 64 lanes -> 1 value/lane (30 shuffles) ----
#pragma unroll
        for (int stage = 0; stage < 4; ++stage) {
            const int mask = 32 >> stage;
            const int half = 8 >> stage;
            const bool hi = (lane & mask) != 0;
#pragma unroll
            for (int i = 0; i < half; ++i) {
                float plo = __shfl_xor(acc[i],        mask);
                float phi = __shfl_xor(acc[i + half], mask);
                acc[i] = hi ? (acc[i + half] + phi) : (acc[i] + plo);
            }
        }
        float acc0 = acc[0];
        acc0 += __shfl_xor(acc0, 1);   // finish sum within the quad
        acc0 += __shfl_xor(acc0, 2);

        if ((lane & 3) == 0) pr[b][wave][lane >> 2] = acc0;
        __syncthreads();               // B1: pr matrix ready

        // ---- cross-wave fold: wave w reduces local row w; Adam in regs ----
        float unew = ucur;
        if (lane < 16) {
            float p = pr[b][lane][wave];
            p += __shfl_xor(p, 1);
            p += __shfl_xor(p, 2);
            p += __shfl_xor(p, 4);
            p += __shfl_xor(p, 8);
            const float g = p;

            b1p *= B1C;
            b2p *= B2C;
            m = B1C * m + (1.0f - B1C) * g;
            v = B2C * v + (1.0f - B2C) * g * g;
            const float denom = sqrtf(v) / sqrtf(1.0f - b2p) + EPSC;
            unew = ucur - (0.1f / (1.0f - b1p)) * m / denom;
            ucur = unew;
        }

        if (t < NSTEPS) {              // nobody consumes u_199 from memory
            if (lane == 0)
                __hip_atomic_store(uout + row, unew, __ATOMIC_RELAXED,
                                   __HIP_MEMORY_SCOPE_AGENT);
            // B2: each wave's s_waitcnt vmcnt(0) before s_barrier drains its
            // u store -> release ordering for the flag below.
            __syncthreads();

            if (tid == 0)
                __hip_atomic_store(flags + (size_t)t * NBLK + bid, 1,
                                   __ATOMIC_RELAXED, __HIP_MEMORY_SCOPE_AGENT);

            if (bid == 0) {
                // aggregator: sole poller of the 256 flags (8 lines)
                if (tid < 64) {
                    const u64* f64 = (const u64*)(flags + (size_t)t * NBLK);
                    const u64 PAIR = 0x0000000100000001ULL;
                    int spin = 0;
                    for (;;) {
                        u64 a = __hip_atomic_load(f64 + lane,      __ATOMIC_RELAXED, __HIP_MEMORY_SCOPE_AGENT);
                        u64 c = __hip_atomic_load(f64 + lane + 64, __ATOMIC_RELAXED, __HIP_MEMORY_SCOPE_AGENT);
                        if (__all((a == PAIR) & (c == PAIR))) break;
                        if (++spin > (1 << 24)) break;   // fail visibly, never hang
                    }
                    if (tid == 0)
                        __hip_atomic_store(go + t, 1, __ATOMIC_RELAXED,
                                           __HIP_MEMORY_SCOPE_AGENT);
                }
            } else {
                // one lane per block polls the single go line
                if (tid == 0) {
                    int spin = 0;
                    while (__hip_atomic_load(go + t, __ATOMIC_RELAXED,
                                             __HIP_MEMORY_SCOPE_AGENT) == 0) {
                        if (++spin > (1 << 24)) break;   // fail visibly, never hang
                    }
                }
            }
            __syncthreads();           // B3: go observed -> u_t fully visible

            // ---- load u_t segment for next iteration (2x8B, 16 B/lane) ----
            u64 d0 = __hip_atomic_load((const u64*)(uout + col0),     __ATOMIC_RELAXED, __HIP_MEMORY_SCOPE_AGENT);
            u64 d1 = __hip_atomic_load((const u64*)(uout + col0 + 2), __ATOMIC_RELAXED, __HIP_MEMORY_SCOPE_AGENT);
            uv0 = __uint_as_float((unsigned)d0);  uv1 = __uint_as_float((unsigned)(d0 >> 32));
            uv2 = __uint_as_float((unsigned)d1);  uv3 = __uint_as_float((unsigned)(d1 >> 32));
        }
    }

    if (lane == 0) w_out[row] = ucur + mrow;
}

extern "C" void kernel_launch(void* const* d_in, const int* in_sizes, int n_in,
                              void* d_out, int out_size, void* d_ws, size_t ws_size,
                              hipStream_t stream) {
    const float* mean = (const float*)d_in[0];   // (4096,)
    const float* va   = (const float*)d_in[1];   // (4096,4096)
    float* w_out = (float*)d_out;                // (4096,)

    float* ws = (float*)d_ws;
    float* u0  = ws;                              // 16 KB
    float* u1  = u0 + MDIM;                       // 16 KB
    int*   flg = (int*)(u1 + MDIM);               // (NSTEPS+1)*256 ints
    int*   go  = flg + (NSTEPS + 1) * NBLK;       // (NSTEPS+1) ints

    const int nflags = (NSTEPS + 1) * NBLK + (NSTEPS + 1);

    init_state<<<(nflags + 255) / 256, 256, 0, stream>>>(mean, u0, flg, nflags);

    void* args[] = { (void*)&va, (void*)&u0, (void*)&u1,
                     (void*)&mean, (void*)&w_out, (void*)&flg, (void*)&go };
    hipLaunchCooperativeKernel((const void*)adam_persist,
                               dim3(NBLK), dim3(NTHR), args, 0, stream);
}